// Round 2
// baseline (1440.163 us; speedup 1.0000x reference)
//
#include <hip/hip_runtime.h>

typedef unsigned short u16;
typedef unsigned int u32;

#define TOK   8192      // T = BS*SLEN
#define DIMK  2048
#define HIDN  1792
#define NEXP  8
#define NPAIR 16384     // T * TOPK
#define MAXROWS 17408   // NPAIR + NEXP*128 padding
#define MAXTILES 136

typedef float f32x4 __attribute__((ext_vector_type(4)));
typedef __bf16 bf16x8 __attribute__((ext_vector_type(8)));

__device__ __forceinline__ u16 f2bf(float f) {
    u32 u = __float_as_uint(f);
    u += 0x7fffu + ((u >> 16) & 1u);   // RNE
    return (u16)(u >> 16);
}

__device__ __forceinline__ void gll16(const void* g, void* l) {
    __builtin_amdgcn_global_load_lds((__attribute__((address_space(1))) void*)(g),
                                     (__attribute__((address_space(3))) void*)(l),
                                     16, 0, 0);
}

// ---------------- transpose + fp32->bf16 : In[R][C] -> Out[C][R] (bf16) ------
__global__ void transpose_f2bf(const float* __restrict__ In, u16* __restrict__ Out,
                               int R, int C) {
    __shared__ float tile[64 * 65];
    size_t moff = (size_t)blockIdx.z * R * C;
    const float* in = In + moff;
    u16* out = Out + moff;
    int c0 = blockIdx.x * 64, r0 = blockIdx.y * 64;
    int tid = threadIdx.x;
#pragma unroll
    for (int p = 0; p < 16; ++p) {
        int idx = tid + p * 256;
        int r = idx >> 6, c = idx & 63;
        tile[r * 65 + c] = in[(size_t)(r0 + r) * C + c0 + c];
    }
    __syncthreads();
#pragma unroll
    for (int p = 0; p < 8; ++p) {
        int idx = (tid + p * 256) * 2;
        int ro = idx >> 6;        // output row within tile (orig col)
        int co = idx & 63;        // output col within tile (orig row), even
        float v0 = tile[co * 65 + ro];
        float v1 = tile[(co + 1) * 65 + ro];
        u32 u = (u32)f2bf(v0) | ((u32)f2bf(v1) << 16);
        *(u32*)&out[(size_t)(c0 + ro) * R + r0 + co] = u;
    }
}

// ---------------- fp32 -> bf16 elementwise (x) ------------------------------
__global__ void cvt_f2bf(const float* __restrict__ in, u16* __restrict__ out, int n8) {
    int i = blockIdx.x * 256 + threadIdx.x;
    if (i >= n8) return;
    const float4* p = (const float4*)in;
    float4 a = p[2 * i], b = p[2 * i + 1];
    union { u16 us[8]; uint4 u4; } o;
    o.us[0] = f2bf(a.x); o.us[1] = f2bf(a.y); o.us[2] = f2bf(a.z); o.us[3] = f2bf(a.w);
    o.us[4] = f2bf(b.x); o.us[5] = f2bf(b.y); o.us[6] = f2bf(b.z); o.us[7] = f2bf(b.w);
    ((uint4*)out)[i] = o.u4;
}

// ---------------- router: fp32 logits, softmax, top-2, slot alloc -----------
__global__ void router_k(const float* __restrict__ x, const float* __restrict__ gw,
                         const float* __restrict__ ebias, int* __restrict__ sel,
                         float* __restrict__ scor, int* __restrict__ pos,
                         int* __restrict__ counts) {
    int wave = threadIdx.x >> 6, lane = threadIdx.x & 63;
    int t = blockIdx.x * 4 + wave;
    const float* xr = x + (size_t)t * DIMK;
    float acc[8];
#pragma unroll
    for (int e = 0; e < 8; ++e) acc[e] = 0.f;
    for (int i = lane; i < DIMK; i += 64) {
        float xv = xr[i];
        float4 g0 = *(const float4*)(gw + (size_t)i * 8);
        float4 g1 = *(const float4*)(gw + (size_t)i * 8 + 4);
        acc[0] += xv * g0.x; acc[1] += xv * g0.y; acc[2] += xv * g0.z; acc[3] += xv * g0.w;
        acc[4] += xv * g1.x; acc[5] += xv * g1.y; acc[6] += xv * g1.z; acc[7] += xv * g1.w;
    }
#pragma unroll
    for (int off = 32; off; off >>= 1)
#pragma unroll
        for (int e = 0; e < 8; ++e) acc[e] += __shfl_xor(acc[e], off, 64);
    if (lane == 0) {
        float mx = acc[0];
#pragma unroll
        for (int e = 1; e < 8; ++e) mx = fmaxf(mx, acc[e]);
        float pv[8], psum = 0.f;
#pragma unroll
        for (int e = 0; e < 8; ++e) { pv[e] = __expf(acc[e] - mx); psum += pv[e]; }
        float inv = 1.f / psum;
        float bb[8];
#pragma unroll
        for (int e = 0; e < 8; ++e) { pv[e] *= inv; bb[e] = pv[e] + ebias[e]; }
        int e0 = 0;
#pragma unroll
        for (int e = 1; e < 8; ++e) if (bb[e] > bb[e0]) e0 = e;
        int e1 = (e0 == 0) ? 1 : 0;
#pragma unroll
        for (int e = 0; e < 8; ++e) if (e != e0 && bb[e] > bb[e1]) e1 = e;
        int i0 = t * 2, i1 = t * 2 + 1;
        sel[i0] = e0; sel[i1] = e1;
        scor[i0] = pv[e0]; scor[i1] = pv[e1];
        pos[i0] = atomicAdd(&counts[e0], 1);
        pos[i1] = atomicAdd(&counts[e1], 1);
    }
}

// ---------------- scan: 128-aligned segments + tile map ---------------------
__global__ void scan_k(const int* __restrict__ counts, int* __restrict__ seg,
                       int* __restrict__ tile_e, int* __restrict__ tile_r0,
                       int* __restrict__ ntile) {
    if (threadIdx.x == 0 && blockIdx.x == 0) {
        int off = 0, nt = 0;
        for (int e = 0; e < NEXP; ++e) {
            seg[e] = off;
            int c = counts[e];
            int tiles = (c + 127) >> 7;
            for (int j = 0; j < tiles; ++j) { tile_e[nt] = e; tile_r0[nt] = off + (j << 7); ++nt; }
            off += tiles << 7;
        }
        *ntile = nt;
    }
}

// ---------------- dispatch: gather+scale to bf16, plus pad-row zeroing ------
__global__ void dispatch_k(const float* __restrict__ x, const int* __restrict__ sel,
                           const float* __restrict__ scor, const int* __restrict__ pos,
                           const int* __restrict__ counts, const int* __restrict__ seg,
                           u32* __restrict__ rin, int* __restrict__ tok) {
    int b = blockIdx.x;
    if (b < NPAIR) {
        int t = b >> 1;
        int e = sel[b];
        float s = scor[b];
        int row = seg[e] + pos[b];
        const float2* xr = (const float2*)(x + (size_t)t * DIMK);
        u32* orow = rin + (size_t)row * (DIMK / 2);
        for (int i = threadIdx.x; i < DIMK / 2; i += 256) {
            float2 v = xr[i];
            orow[i] = (u32)f2bf(v.x * s) | ((u32)f2bf(v.y * s) << 16);
        }
        if (threadIdx.x == 0) tok[row] = t;
    } else {
        int pb = b - NPAIR;
        int e = pb >> 7, j = pb & 127;
        int c = counts[e];
        int al = (c + 127) & ~127;
        if (c + j < al) {
            int row = seg[e] + c + j;
            u32* orow = rin + (size_t)row * (DIMK / 2);
            for (int i = threadIdx.x; i < DIMK / 2; i += 256) orow[i] = 0u;
            if (threadIdx.x == 0) tok[row] = -1;
        }
    }
}

// ---------------- GEMM1 fused: h = silu(A@W1) * (A@W3), bf16 out ------------
// A [rows][2048] bf16 row-major; B1g/B3g are W^T: [1792][2048] bf16 per expert.
template <bool GROUPED>
__launch_bounds__(256, 2)
__global__ void gemm_h(const u16* __restrict__ A, const u16* __restrict__ B1g,
                       const u16* __restrict__ B3g, u16* __restrict__ H,
                       const int* __restrict__ tile_e, const int* __restrict__ tile_r0,
                       const int* __restrict__ ntile) {
    constexpr int Kd = DIMK;   // 2048
    constexpr int Nd = HIDN;   // 1792
    __shared__ u16 As[128 * 32];
    __shared__ u16 B1s[128 * 32];
    __shared__ u16 B3s[128 * 32];
    int bx = blockIdx.x;
    int r0; size_t woff = 0;
    if constexpr (GROUPED) {
        if (bx >= *ntile) return;
        r0 = tile_r0[bx];
        woff = (size_t)tile_e[bx] * (size_t)Nd * Kd;
    } else {
        r0 = bx * 128;
    }
    int c0 = blockIdx.y * 128;
    int tid = threadIdx.x, wave = tid >> 6, lane = tid & 63;
    int srow = wave * 16 + (lane >> 2);
    int skc = (lane & 3) * 8;
    const u16* gA0 = A + (size_t)(r0 + srow) * Kd + skc;
    const u16* gA1 = gA0 + (size_t)64 * Kd;
    const u16* gB1a = B1g + woff + (size_t)(c0 + srow) * Kd + skc;
    const u16* gB1b = gB1a + (size_t)64 * Kd;
    const u16* gB3a = B3g + woff + (size_t)(c0 + srow) * Kd + skc;
    const u16* gB3b = gB3a + (size_t)64 * Kd;
    char* lA0 = (char*)As + wave * 1024;   char* lA1 = (char*)As + 4096 + wave * 1024;
    char* lB1a = (char*)B1s + wave * 1024; char* lB1b = (char*)B1s + 4096 + wave * 1024;
    char* lB3a = (char*)B3s + wave * 1024; char* lB3b = (char*)B3s + 4096 + wave * 1024;

    int wr = wave >> 1, wc = wave & 1;
    int fr = lane & 15, fq = lane >> 4;
    const u16* fA = As + (wr * 64 + fr) * 32 + fq * 8;
    const u16* fB1 = B1s + (wc * 64 + fr) * 32 + fq * 8;
    const u16* fB3 = B3s + (wc * 64 + fr) * 32 + fq * 8;

    f32x4 acc1[4][4], acc3[4][4];
    f32x4 zz = {0.f, 0.f, 0.f, 0.f};
#pragma unroll
    for (int m = 0; m < 4; ++m)
#pragma unroll
        for (int n = 0; n < 4; ++n) { acc1[m][n] = zz; acc3[m][n] = zz; }

    for (int kt = 0; kt < Kd / 32; ++kt) {
        int ko = kt * 32;
        gll16(gA0 + ko, lA0);  gll16(gA1 + ko, lA1);
        gll16(gB1a + ko, lB1a); gll16(gB1b + ko, lB1b);
        gll16(gB3a + ko, lB3a); gll16(gB3b + ko, lB3b);
        __syncthreads();
        bf16x8 aF[4], b1F[4], b3F[4];
#pragma unroll
        for (int m = 0; m < 4; ++m) aF[m] = *(const bf16x8*)(fA + m * 16 * 32);
#pragma unroll
        for (int n = 0; n < 4; ++n) {
            b1F[n] = *(const bf16x8*)(fB1 + n * 16 * 32);
            b3F[n] = *(const bf16x8*)(fB3 + n * 16 * 32);
        }
#pragma unroll
        for (int m = 0; m < 4; ++m)
#pragma unroll
            for (int n = 0; n < 4; ++n) {
                acc1[m][n] = __builtin_amdgcn_mfma_f32_16x16x32_bf16(aF[m], b1F[n], acc1[m][n], 0, 0, 0);
                acc3[m][n] = __builtin_amdgcn_mfma_f32_16x16x32_bf16(aF[m], b3F[n], acc3[m][n], 0, 0, 0);
            }
        __syncthreads();
    }
#pragma unroll
    for (int m = 0; m < 4; ++m) {
#pragma unroll
        for (int n = 0; n < 4; ++n) {
            int gcol = c0 + wc * 64 + n * 16 + fr;
#pragma unroll
            for (int i = 0; i < 4; ++i) {
                int grow = r0 + wr * 64 + m * 16 + fq * 4 + i;
                float p1 = acc1[m][n][i], p3 = acc3[m][n][i];
                float h = p1 * p3 / (1.f + __expf(-p1));
                H[(size_t)grow * Nd + gcol] = f2bf(h);
            }
        }
    }
}

// ---------------- GEMM2: out = A @ W2 ; MODE 0 store, MODE 1 atomic scatter -
// A [rows][1792] bf16; Bg = W2^T: [2048][1792] bf16 per expert.
template <int MODE>
__launch_bounds__(256, 2)
__global__ void gemm_o(const u16* __restrict__ A, const u16* __restrict__ Bg,
                       float* __restrict__ Out,
                       const int* __restrict__ tile_e, const int* __restrict__ tile_r0,
                       const int* __restrict__ ntile, const int* __restrict__ tok) {
    constexpr int Kd = HIDN;   // 1792
    constexpr int Nd = DIMK;   // 2048
    __shared__ u16 As[128 * 32];
    __shared__ u16 Bs[128 * 32];
    int bx = blockIdx.x;
    int r0; size_t woff = 0;
    if constexpr (MODE == 1) {
        if (bx >= *ntile) return;
        r0 = tile_r0[bx];
        woff = (size_t)tile_e[bx] * (size_t)Nd * Kd;
    } else {
        r0 = bx * 128;
    }
    int c0 = blockIdx.y * 128;
    int tid = threadIdx.x, wave = tid >> 6, lane = tid & 63;
    int srow = wave * 16 + (lane >> 2);
    int skc = (lane & 3) * 8;
    const u16* gA0 = A + (size_t)(r0 + srow) * Kd + skc;
    const u16* gA1 = gA0 + (size_t)64 * Kd;
    const u16* gB0 = Bg + woff + (size_t)(c0 + srow) * Kd + skc;
    const u16* gB1 = gB0 + (size_t)64 * Kd;
    char* lA0 = (char*)As + wave * 1024; char* lA1 = (char*)As + 4096 + wave * 1024;
    char* lB0 = (char*)Bs + wave * 1024; char* lB1 = (char*)Bs + 4096 + wave * 1024;
    int wr = wave >> 1, wc = wave & 1;
    int fr = lane & 15, fq = lane >> 4;
    const u16* fA = As + (wr * 64 + fr) * 32 + fq * 8;
    const u16* fB = Bs + (wc * 64 + fr) * 32 + fq * 8;
    f32x4 acc[4][4];
    f32x4 zz = {0.f, 0.f, 0.f, 0.f};
#pragma unroll
    for (int m = 0; m < 4; ++m)
#pragma unroll
        for (int n = 0; n < 4; ++n) acc[m][n] = zz;
    for (int kt = 0; kt < Kd / 32; ++kt) {
        int ko = kt * 32;
        gll16(gA0 + ko, lA0); gll16(gA1 + ko, lA1);
        gll16(gB0 + ko, lB0); gll16(gB1 + ko, lB1);
        __syncthreads();
        bf16x8 aF[4], bF[4];
#pragma unroll
        for (int m = 0; m < 4; ++m) aF[m] = *(const bf16x8*)(fA + m * 16 * 32);
#pragma unroll
        for (int n = 0; n < 4; ++n) bF[n] = *(const bf16x8*)(fB + n * 16 * 32);
#pragma unroll
        for (int m = 0; m < 4; ++m)
#pragma unroll
            for (int n = 0; n < 4; ++n)
                acc[m][n] = __builtin_amdgcn_mfma_f32_16x16x32_bf16(aF[m], bF[n], acc[m][n], 0, 0, 0);
        __syncthreads();
    }
#pragma unroll
    for (int m = 0; m < 4; ++m) {
        int tkv[4];
        if constexpr (MODE == 1) {
#pragma unroll
            for (int i = 0; i < 4; ++i) tkv[i] = tok[r0 + wr * 64 + m * 16 + fq * 4 + i];
        }
#pragma unroll
        for (int n = 0; n < 4; ++n) {
            int gcol = c0 + wc * 64 + n * 16 + fr;
#pragma unroll
            for (int i = 0; i < 4; ++i) {
                float v = acc[m][n][i];
                if constexpr (MODE == 0) {
                    int grow = r0 + wr * 64 + m * 16 + fq * 4 + i;
                    Out[(size_t)grow * Nd + gcol] = v;
                } else {
                    int t2 = tkv[i];
                    if (t2 >= 0) atomicAdd(&Out[(size_t)t2 * Nd + gcol], v);
                }
            }
        }
    }
}

// ----------------------------------------------------------------------------
extern "C" void kernel_launch(void* const* d_in, const int* in_sizes, int n_in,
                              void* d_out, int out_size, void* d_ws, size_t ws_size,
                              hipStream_t stream) {
    const float* x    = (const float*)d_in[0];
    const float* gw   = (const float*)d_in[1];
    const float* w1   = (const float*)d_in[2];
    const float* w2   = (const float*)d_in[3];
    const float* w3   = (const float*)d_in[4];
    const float* sw1  = (const float*)d_in[5];
    const float* sw2  = (const float*)d_in[6];
    const float* sw3  = (const float*)d_in[7];
    const float* ebias= (const float*)d_in[8];
    float* out = (float*)d_out;

    char* p = (char*)d_ws;
    auto alloc = [&](size_t b) -> char* {
        char* r = p; p += (b + 255) & ~(size_t)255; return r;
    };
    u16* w1b  = (u16*)alloc((size_t)NEXP * HIDN * DIMK * 2);
    u16* w3b  = (u16*)alloc((size_t)NEXP * HIDN * DIMK * 2);
    u16* w2b  = (u16*)alloc((size_t)NEXP * DIMK * HIDN * 2);
    u16* sw1b = (u16*)alloc((size_t)HIDN * DIMK * 2);
    u16* sw3b = (u16*)alloc((size_t)HIDN * DIMK * 2);
    u16* sw2b = (u16*)alloc((size_t)DIMK * HIDN * 2);
    u16* xb   = (u16*)alloc((size_t)TOK * DIMK * 2);
    u16* rin  = (u16*)alloc((size_t)MAXROWS * DIMK * 2);
    u16* hbuf = (u16*)alloc((size_t)MAXROWS * HIDN * 2);
    int* sel    = (int*)alloc(NPAIR * 4);
    float* scor = (float*)alloc(NPAIR * 4);
    int* pos    = (int*)alloc(NPAIR * 4);
    int* counts = (int*)alloc(64);
    int* seg    = (int*)alloc(64);
    int* tile_e = (int*)alloc(256 * 4);
    int* tile_r0= (int*)alloc(256 * 4);
    int* ntile  = (int*)alloc(64);
    int* tok    = (int*)alloc(MAXROWS * 4);

    hipMemsetAsync(counts, 0, NEXP * 4, stream);

    // weight transpose + bf16 convert
    transpose_f2bf<<<dim3(HIDN / 64, DIMK / 64, NEXP), 256, 0, stream>>>(w1, w1b, DIMK, HIDN);
    transpose_f2bf<<<dim3(HIDN / 64, DIMK / 64, NEXP), 256, 0, stream>>>(w3, w3b, DIMK, HIDN);
    transpose_f2bf<<<dim3(DIMK / 64, HIDN / 64, NEXP), 256, 0, stream>>>(w2, w2b, HIDN, DIMK);
    transpose_f2bf<<<dim3(HIDN / 64, DIMK / 64, 1), 256, 0, stream>>>(sw1, sw1b, DIMK, HIDN);
    transpose_f2bf<<<dim3(HIDN / 64, DIMK / 64, 1), 256, 0, stream>>>(sw3, sw3b, DIMK, HIDN);
    transpose_f2bf<<<dim3(DIMK / 64, HIDN / 64, 1), 256, 0, stream>>>(sw2, sw2b, HIDN, DIMK);

    cvt_f2bf<<<(TOK * DIMK / 8 + 255) / 256, 256, 0, stream>>>(x, xb, TOK * DIMK / 8);
    router_k<<<TOK / 4, 256, 0, stream>>>(x, gw, ebias, sel, scor, pos, counts);
    scan_k<<<1, 64, 0, stream>>>(counts, seg, tile_e, tile_r0, ntile);
    dispatch_k<<<NPAIR + NEXP * 128, 256, 0, stream>>>(x, sel, scor, pos, counts, seg,
                                                       (u32*)rin, tok);

    // shared expert: h = silu(x@sw1)*(x@sw3); out = h@sw2 (plain store, inits d_out)
    gemm_h<false><<<dim3(TOK / 128, HIDN / 128), 256, 0, stream>>>(
        xb, sw1b, sw3b, hbuf, nullptr, nullptr, nullptr);
    gemm_o<0><<<dim3(TOK / 128, DIMK / 128), 256, 0, stream>>>(
        hbuf, sw2b, out, nullptr, nullptr, nullptr, nullptr);

    // routed experts: grouped GEMMs + atomic scatter-add
    gemm_h<true><<<dim3(MAXTILES, HIDN / 128), 256, 0, stream>>>(
        rin, w1b, w3b, hbuf, tile_e, tile_r0, ntile);
    gemm_o<1><<<dim3(MAXTILES, DIMK / 128), 256, 0, stream>>>(
        hbuf, w2b, out, tile_e, tile_r0, ntile, tok);
}

// Round 5
// 1343.201 us; speedup vs baseline: 1.0722x; 1.0722x over previous
//
#include <hip/hip_runtime.h>

typedef unsigned short u16;
typedef unsigned int u32;

#define TOK    8192      // T = BS*SLEN
#define DIMK   2048
#define HIDN   1792
#define NCAT   3584      // 2*HIDN (interleaved W1/W3 rows)
#define NEXP   8
#define NPAIR  16384     // T * TOPK
#define RROWS  18432     // routed rows capacity (16384 + 8*256 pad)
#define CROWS  26624     // combined rows capacity (TOK + RROWS)
#define MAXMT  104       // 32 shared tiles + 72 routed tiles

typedef float f32x4 __attribute__((ext_vector_type(4)));
typedef __bf16 bf16x8 __attribute__((ext_vector_type(8)));

__device__ __forceinline__ u16 f2bf(float f) {
    u32 u = __float_as_uint(f);
    u += 0x7fffu + ((u >> 16) & 1u);   // RNE
    return (u16)(u >> 16);
}
__device__ __forceinline__ void gll16(const void* g, void* l) {
    __builtin_amdgcn_global_load_lds((__attribute__((address_space(1))) void*)(g),
                                     (__attribute__((address_space(3))) void*)(l),
                                     16, 0, 0);
}

// ------ transpose + fp32->bf16 : In[z][R][C] -> Out[z][C][R]  ---------------
// ilv=0: row r -> r.  ilv=1/2: W1/W3 16-col-group interleave:
//   r -> (r&~15)*2 + (ilv==2 ? 16 : 0) + (r&15)
__global__ void transpose_f2bf(const float* __restrict__ In, u16* __restrict__ Out,
                               int R, int C, size_t in_z, size_t out_z, size_t out_off,
                               int ilv) {
    __shared__ float tile[64 * 65];
    const float* in = In + (size_t)blockIdx.z * in_z;
    u16* out = Out + (size_t)blockIdx.z * out_z + out_off;
    int c0 = blockIdx.x * 64, r0 = blockIdx.y * 64;
    int tid = threadIdx.x;
#pragma unroll
    for (int p = 0; p < 16; ++p) {
        int idx = tid + p * 256;
        int r = idx >> 6, c = idx & 63;
        tile[r * 65 + c] = in[(size_t)(r0 + r) * C + c0 + c];
    }
    __syncthreads();
#pragma unroll
    for (int p = 0; p < 8; ++p) {
        int idx = (tid + p * 256) * 2;
        int ro = idx >> 6;
        int co = idx & 63;
        float v0 = tile[co * 65 + ro];
        float v1 = tile[(co + 1) * 65 + ro];
        u32 u = (u32)f2bf(v0) | ((u32)f2bf(v1) << 16);
        int orow = c0 + ro;
        if (ilv) orow = ((orow & ~15) << 1) + (ilv == 2 ? 16 : 0) + (orow & 15);
        *(u32*)&out[(size_t)orow * R + r0 + co] = u;
    }
}

// ---------------- fp32 -> bf16 elementwise (x) ------------------------------
__global__ void cvt_f2bf(const float* __restrict__ in, u16* __restrict__ out, int n8) {
    int i = blockIdx.x * 256 + threadIdx.x;
    if (i >= n8) return;
    const float4* p = (const float4*)in;
    float4 a = p[2 * i], b = p[2 * i + 1];
    union { u16 us[8]; uint4 u4; } o;
    o.us[0] = f2bf(a.x); o.us[1] = f2bf(a.y); o.us[2] = f2bf(a.z); o.us[3] = f2bf(a.w);
    o.us[4] = f2bf(b.x); o.us[5] = f2bf(b.y); o.us[6] = f2bf(b.z); o.us[7] = f2bf(b.w);
    ((uint4*)out)[i] = o.u4;
}

// ---------------- router: fp32 logits, softmax, top-2, slot alloc -----------
__global__ void router_k(const float* __restrict__ x, const float* __restrict__ gw,
                         const float* __restrict__ ebias, int* __restrict__ sel,
                         float* __restrict__ scor, int* __restrict__ pos,
                         int* __restrict__ counts) {
    int wave = threadIdx.x >> 6, lane = threadIdx.x & 63;
    int t = blockIdx.x * 4 + wave;
    const float* xr = x + (size_t)t * DIMK;
    float acc[8];
#pragma unroll
    for (int e = 0; e < 8; ++e) acc[e] = 0.f;
    for (int i = lane; i < DIMK; i += 64) {
        float xv = xr[i];
        float4 g0 = *(const float4*)(gw + (size_t)i * 8);
        float4 g1 = *(const float4*)(gw + (size_t)i * 8 + 4);
        acc[0] += xv * g0.x; acc[1] += xv * g0.y; acc[2] += xv * g0.z; acc[3] += xv * g0.w;
        acc[4] += xv * g1.x; acc[5] += xv * g1.y; acc[6] += xv * g1.z; acc[7] += xv * g1.w;
    }
#pragma unroll
    for (int off = 32; off; off >>= 1)
#pragma unroll
        for (int e = 0; e < 8; ++e) acc[e] += __shfl_xor(acc[e], off, 64);
    if (lane == 0) {
        float mx = acc[0];
#pragma unroll
        for (int e = 1; e < 8; ++e) mx = fmaxf(mx, acc[e]);
        float pv[8], psum = 0.f;
#pragma unroll
        for (int e = 0; e < 8; ++e) { pv[e] = __expf(acc[e] - mx); psum += pv[e]; }
        float inv = 1.f / psum;
        float bb[8];
#pragma unroll
        for (int e = 0; e < 8; ++e) { pv[e] *= inv; bb[e] = pv[e] + ebias[e]; }
        int e0 = 0;
#pragma unroll
        for (int e = 1; e < 8; ++e) if (bb[e] > bb[e0]) e0 = e;
        int e1 = (e0 == 0) ? 1 : 0;
#pragma unroll
        for (int e = 0; e < 8; ++e) if (e != e0 && bb[e] > bb[e1]) e1 = e;
        int i0 = t * 2, i1 = t * 2 + 1;
        sel[i0] = e0; sel[i1] = e1;
        scor[i0] = pv[e0]; scor[i1] = pv[e1];
        pos[i0] = atomicAdd(&counts[e0], 1);
        pos[i1] = atomicAdd(&counts[e1], 1);
    }
}

// ---------------- scan: 256-aligned segments + combined tile map ------------
__global__ void scan_k(const int* __restrict__ counts, int* __restrict__ seg,
                       int* __restrict__ mt_e, int* __restrict__ mt_r0,
                       int* __restrict__ nmt, int* __restrict__ nrows) {
    if (threadIdx.x == 0 && blockIdx.x == 0) {
        int ntl = 0;
        for (int i = 0; i < TOK / 256; ++i) { mt_e[ntl] = 8; mt_r0[ntl] = i * 256; ++ntl; }
        int off = TOK;
        for (int e = 0; e < NEXP; ++e) {
            seg[e] = off;
            int c = counts[e];
            int tl = (c + 255) >> 8;
            for (int j = 0; j < tl; ++j) { mt_e[ntl] = e; mt_r0[ntl] = off + (j << 8); ++ntl; }
            off += tl << 8;
        }
        *nmt = ntl;
        *nrows = off;
    }
}

// ---------------- dispatch: gather+scale to bf16, plus pad-row zeroing ------
__global__ void dispatch_k(const float* __restrict__ x, const int* __restrict__ sel,
                           const float* __restrict__ scor, const int* __restrict__ pos,
                           const int* __restrict__ counts, const int* __restrict__ seg,
                           u32* __restrict__ rin, int* __restrict__ tok) {
    int b = blockIdx.x;
    if (b < NPAIR) {
        int t = b >> 1;
        int e = sel[b];
        float s = scor[b];
        int row = seg[e] + pos[b];           // combined row (>= TOK)
        const float2* xr = (const float2*)(x + (size_t)t * DIMK);
        u32* orow = rin + (size_t)(row - TOK) * (DIMK / 2);
        for (int i = threadIdx.x; i < DIMK / 2; i += 256) {
            float2 v = xr[i];
            orow[i] = (u32)f2bf(v.x * s) | ((u32)f2bf(v.y * s) << 16);
        }
        if (threadIdx.x == 0) tok[row] = t;
    } else {
        int pb = b - NPAIR;
        int e = pb >> 8, j = pb & 255;
        int c = counts[e];
        int al = (c + 255) & ~255;
        if (c + j < al) {
            int row = seg[e] + c + j;
            u32* orow = rin + (size_t)(row - TOK) * (DIMK / 2);
            for (int i = threadIdx.x; i < DIMK / 2; i += 256) orow[i] = 0u;
            if (threadIdx.x == 0) tok[row] = -1;
        }
    }
}

// ================= 256x256 8-phase GEMM (m201 template, plain HIP) ==========
// A [rows][ASTR] bf16; B cat [9][ND][KD] bf16 (B^T per expert).
// EPI 0: paired silu-mul -> bf16 H[r][ND/2]   (gemm1, W1/W3 interleaved)
// EPI 1: store f32 -> out (shared rows); EPI 2: atomicAdd f32 -> out[tok[r]].
#define LDA(mh, b) { \
    _Pragma("unroll") for (int m_ = 0; m_ < 4; ++m_) \
    _Pragma("unroll") for (int ks_ = 0; ks_ < 2; ++ks_) \
        aF[mh][m_][ks_] = *(const bf16x8*)(&lds[b][0][0] + aRd + ((mh)*4 + m_) * 2048 + ks_ * 64); }
#define LDB(nh, b) { \
    _Pragma("unroll") for (int n_ = 0; n_ < 2; ++n_) \
    _Pragma("unroll") for (int ks_ = 0; ks_ < 2; ++ks_) \
        bF[n_][ks_] = *(const bf16x8*)(&lds[b][1][0] + bRd + ((nh)*2 + n_) * 2048 + ks_ * 64); }
#define MFMAQ(mh, nh) { \
    _Pragma("unroll") for (int m_ = 0; m_ < 4; ++m_) \
    _Pragma("unroll") for (int n_ = 0; n_ < 2; ++n_) \
    _Pragma("unroll") for (int ks_ = 0; ks_ < 2; ++ks_) \
        acc[(mh)*4 + m_][(nh)*2 + n_] = __builtin_amdgcn_mfma_f32_16x16x32_bf16( \
            aF[mh][m_][ks_], bF[n_][ks_], acc[(mh)*4 + m_][(nh)*2 + n_], 0, 0, 0); }
#define SA(kt, half, b) do { \
    const char* s_ = gA + (size_t)(half) * (128 * ABS) + (size_t)(kt) * 128; \
    char* d_ = &lds[b][0][0] + (half) * 16384 + t16; \
    gll16(s_, d_); gll16(s_ + 64 * ABS, d_ + 8192); } while (0)
#define SB(kt, half, b) do { \
    const char* s_ = gB + (size_t)(half) * (128 * BBS) + (size_t)(kt) * 128; \
    char* d_ = &lds[b][1][0] + (half) * 16384 + t16; \
    gll16(s_, d_); gll16(s_ + 64 * BBS, d_ + 8192); } while (0)
#define PH_SYNC() \
    __builtin_amdgcn_s_barrier(); \
    asm volatile("s_waitcnt lgkmcnt(0)" ::: "memory"); \
    __builtin_amdgcn_sched_barrier(0); \
    __builtin_amdgcn_s_setprio(1)
#define PH_END() \
    __builtin_amdgcn_s_setprio(0); \
    __builtin_amdgcn_s_barrier()

template <int KD, int ND, int ASTR, int EPI>
__launch_bounds__(512, 2)
__global__ void gemm256(const u16* __restrict__ A0, const u16* __restrict__ A1,
                        const u16* __restrict__ Bcat, void* __restrict__ Obase,
                        const int* __restrict__ mt_e, const int* __restrict__ mt_r0,
                        const int* __restrict__ nmt, const int* __restrict__ tok,
                        int tile_off) {
    int my = blockIdx.y + tile_off;
    if (my >= *nmt) return;
    const int e = mt_e[my];
    const int r0 = mt_r0[my];
    const int c0 = blockIdx.x * 256;

    const u16* Ab;
    if constexpr (EPI == 0)
        Ab = (r0 < TOK) ? (A0 + (size_t)r0 * ASTR) : (A1 + (size_t)(r0 - TOK) * ASTR);
    else
        Ab = A0 + (size_t)r0 * ASTR;
    const u16* Bb = Bcat + (size_t)e * ND * KD + (size_t)c0 * KD;

    __shared__ char lds[2][2][32768];   // [dbuf][A/B][256x64 bf16]

    const int t = threadIdx.x;
    const int lane = t & 63;
    const int wid = t >> 6;
    const int wr = wid >> 2, wc = wid & 3;
    const int fr = lane & 15, fq = lane >> 4;
    const int sbit = ((fr >> 2) & 1) << 5;                    // st_16x32 read swizzle
    const int aRd = ((wr * 128 + fr) * 128 + fq * 16) ^ sbit;
    const int bRd = ((wc * 64 + fr) * 128 + fq * 16) ^ sbit;
    const int t16 = t * 16;
    constexpr size_t ABS = (size_t)ASTR * 2;
    constexpr size_t BBS = (size_t)KD * 2;
    const int scb = ((t & 7) * 16) ^ (((t >> 5) & 1) << 5);   // pre-swizzled source col
    const char* gA = (const char*)Ab + (size_t)(t >> 3) * ABS + scb;
    const char* gB = (const char*)Bb + (size_t)(t >> 3) * BBS + scb;

    f32x4 acc[8][4];
    const f32x4 zz = {0.f, 0.f, 0.f, 0.f};
#pragma unroll
    for (int m = 0; m < 8; ++m)
#pragma unroll
        for (int n = 0; n < 4; ++n) acc[m][n] = zz;
    bf16x8 aF[2][4][2], bF[2][2];

    constexpr int NT = KD / 64;
    constexpr int NITER = NT / 2;

    // prologue: A(0),B(0)->buf0, A(1)->buf1; wait K-tile 0 landed
    SA(0, 0, 0); SA(0, 1, 0); SB(0, 0, 0); SB(0, 1, 0);
    SA(1, 0, 1); SA(1, 1, 1);
    asm volatile("s_waitcnt vmcnt(4)" ::: "memory");
    __builtin_amdgcn_s_barrier();

#pragma unroll 1
    for (int it = 0; it < NITER; ++it) {
        const int t0 = 2 * it;
        const bool pf = (t0 + 2 < NT);
        // ph1: Q(0,0) of t0 (buf0); stage B-lo(t0+1)->buf1
        LDA(0, 0); LDB(0, 0);
        SB(t0 + 1, 0, 1);
        PH_SYNC(); MFMAQ(0, 0); PH_END();
        // ph2: Q(1,0); stage B-hi(t0+1)->buf1   [buf0 A fully read after this]
        LDA(1, 0);
        SB(t0 + 1, 1, 1);
        PH_SYNC(); MFMAQ(1, 0); PH_END();
        // ph3: Q(0,1); stage A-lo(t0+2)->buf0   [buf0 B fully read after this]
        LDB(1, 0);
        if (pf) SA(t0 + 2, 0, 0);
        PH_SYNC(); MFMAQ(0, 1); PH_END();
        // ph4: Q(1,1); stage A-hi(t0+2)->buf0; vmcnt -> A(t0+1),B(t0+1) landed
        if (pf) { SA(t0 + 2, 1, 0); asm volatile("s_waitcnt vmcnt(4)" ::: "memory"); }
        else    { asm volatile("s_waitcnt vmcnt(0)" ::: "memory"); }
        PH_SYNC(); MFMAQ(1, 1); PH_END();
        // ph5: Q(0,0) of t0+1 (buf1); stage B-lo(t0+2)->buf0
        LDA(0, 1); LDB(0, 1);
        if (pf) SB(t0 + 2, 0, 0);
        PH_SYNC(); MFMAQ(0, 0); PH_END();
        // ph6: Q(1,0); stage B-hi(t0+2)->buf0   [buf1 A fully read after this]
        LDA(1, 1);
        if (pf) SB(t0 + 2, 1, 0);
        PH_SYNC(); MFMAQ(1, 0); PH_END();
        // ph7: Q(0,1); stage A-lo(t0+3)->buf1   [buf1 B fully read after this]
        LDB(1, 1);
        if (pf) SA(t0 + 3, 0, 1);
        PH_SYNC(); MFMAQ(0, 1); PH_END();
        // ph8: Q(1,1); stage A-hi(t0+3)->buf1; vmcnt -> A(t0+2),B(t0+2) landed
        if (pf) { SA(t0 + 3, 1, 1); asm volatile("s_waitcnt vmcnt(4)" ::: "memory"); }
        PH_SYNC(); MFMAQ(1, 1); PH_END();
    }

    // epilogue
    if constexpr (EPI == 0) {
        // W1/W3 interleaved in 16-col groups: n even = W1, n+1 = W3 (same cols)
        u16* H = (u16*)Obase;
        constexpr int HST = ND / 2;
#pragma unroll
        for (int m = 0; m < 8; ++m) {
#pragma unroll
            for (int n = 0; n < 4; n += 2) {
                int gc = (c0 + wc * 64 + n * 16) / 2 + fr;
#pragma unroll
                for (int i = 0; i < 4; ++i) {
                    int gr = r0 + wr * 128 + m * 16 + fq * 4 + i;
                    float p1 = acc[m][n][i], p3 = acc[m][n + 1][i];
                    float h = p1 * p3 / (1.f + __expf(-p1));
                    H[(size_t)gr * HST + gc] = f2bf(h);
                }
            }
        }
    } else if constexpr (EPI == 1) {
        float* O = (float*)Obase;
#pragma unroll
        for (int m = 0; m < 8; ++m)
#pragma unroll
            for (int n = 0; n < 4; ++n) {
                int gc = c0 + wc * 64 + n * 16 + fr;
#pragma unroll
                for (int i = 0; i < 4; ++i) {
                    int gr = r0 + wr * 128 + m * 16 + fq * 4 + i;
                    O[(size_t)gr * ND + gc] = acc[m][n][i];
                }
            }
    } else {
        float* O = (float*)Obase;
#pragma unroll
        for (int m = 0; m < 8; ++m) {
            int tk[4];
#pragma unroll
            for (int i = 0; i < 4; ++i)
                tk[i] = tok[r0 + wr * 128 + m * 16 + fq * 4 + i];
#pragma unroll
            for (int n = 0; n < 4; ++n) {
                int gc = c0 + wc * 64 + n * 16 + fr;
#pragma unroll
                for (int i = 0; i < 4; ++i)
                    if (tk[i] >= 0) atomicAdd(&O[(size_t)tk[i] * ND + gc], acc[m][n][i]);
            }
        }
    }
}

// ----------------------------------------------------------------------------
extern "C" void kernel_launch(void* const* d_in, const int* in_sizes, int n_in,
                              void* d_out, int out_size, void* d_ws, size_t ws_size,
                              hipStream_t stream) {
    const float* x    = (const float*)d_in[0];
    const float* gw   = (const float*)d_in[1];
    const float* w1   = (const float*)d_in[2];
    const float* w2   = (const float*)d_in[3];
    const float* w3   = (const float*)d_in[4];
    const float* sw1  = (const float*)d_in[5];
    const float* sw2  = (const float*)d_in[6];
    const float* sw3  = (const float*)d_in[7];
    const float* ebias= (const float*)d_in[8];
    float* out = (float*)d_out;

    char* p = (char*)d_ws;
    auto alloc = [&](size_t b) -> char* {
        char* r = p; p += (b + 255) & ~(size_t)255; return r;
    };
    u16* wcat  = (u16*)alloc((size_t)9 * NCAT * DIMK * 2);   // [e<=8][3584 ilv][2048]
    u16* w2cat = (u16*)alloc((size_t)9 * DIMK * HIDN * 2);   // [e<=8][2048][1792]
    u16* xb    = (u16*)alloc((size_t)TOK * DIMK * 2);
    u16* rin   = (u16*)alloc((size_t)RROWS * DIMK * 2);
    u16* hbuf  = (u16*)alloc((size_t)CROWS * HIDN * 2);      // silu-mul'd h
    int* sel    = (int*)alloc(NPAIR * 4);
    float* scor = (float*)alloc(NPAIR * 4);
    int* pos    = (int*)alloc(NPAIR * 4);
    int* counts = (int*)alloc(64);
    int* seg    = (int*)alloc(64);
    int* mt_e   = (int*)alloc(MAXMT * 4);
    int* mt_r0  = (int*)alloc(MAXMT * 4);
    int* nmt    = (int*)alloc(64);
    int* nrows  = (int*)alloc(64);
    int* tok    = (int*)alloc(CROWS * 4);

    hipMemsetAsync(counts, 0, NEXP * 4, stream);

    // weights -> bf16 transposed; wcat = interleaved [W1|W3], expert 8 = shared
    size_t wz = (size_t)NCAT * DIMK;        // 3584*2048
    size_t w2z = (size_t)DIMK * HIDN;       // 2048*1792
    transpose_f2bf<<<dim3(HIDN/64, DIMK/64, NEXP), 256, 0, stream>>>(
        w1, wcat, DIMK, HIDN, (size_t)DIMK*HIDN, wz, 0, 1);
    transpose_f2bf<<<dim3(HIDN/64, DIMK/64, NEXP), 256, 0, stream>>>(
        w3, wcat, DIMK, HIDN, (size_t)DIMK*HIDN, wz, 0, 2);
    transpose_f2bf<<<dim3(HIDN/64, DIMK/64, 1), 256, 0, stream>>>(
        sw1, wcat, DIMK, HIDN, 0, 0, 8*wz, 1);
    transpose_f2bf<<<dim3(HIDN/64, DIMK/64, 1), 256, 0, stream>>>(
        sw3, wcat, DIMK, HIDN, 0, 0, 8*wz, 2);
    transpose_f2bf<<<dim3(DIMK/64, HIDN/64, NEXP), 256, 0, stream>>>(
        w2, w2cat, HIDN, DIMK, (size_t)HIDN*DIMK, w2z, 0, 0);
    transpose_f2bf<<<dim3(DIMK/64, HIDN/64, 1), 256, 0, stream>>>(
        sw2, w2cat, HIDN, DIMK, 0, 0, 8*w2z, 0);

    cvt_f2bf<<<(TOK * DIMK / 8 + 255) / 256, 256, 0, stream>>>(x, xb, TOK * DIMK / 8);
    router_k<<<TOK / 4, 256, 0, stream>>>(x, gw, ebias, sel, scor, pos, counts);
    scan_k<<<1, 64, 0, stream>>>(counts, seg, mt_e, mt_r0, nmt, nrows);
    dispatch_k<<<NPAIR + NEXP * 256, 256, 0, stream>>>(x, sel, scor, pos, counts, seg,
                                                       (u32*)rin, tok);

    // gemm1: h = silu(A@W1)*(A@W3) fused via interleaved weights
    gemm256<DIMK, NCAT, DIMK, 0><<<dim3(NCAT/256, MAXMT), 512, 0, stream>>>(
        xb, rin, wcat, hbuf, mt_e, mt_r0, nmt, nullptr, 0);
    // gemm2 shared tiles: plain f32 store (initializes every out row)
    gemm256<HIDN, DIMK, HIDN, 1><<<dim3(DIMK/256, TOK/256), 512, 0, stream>>>(
        hbuf, nullptr, w2cat, out, mt_e, mt_r0, nmt, nullptr, 0);
    // gemm2 routed tiles: atomic scatter-add into out
    gemm256<HIDN, DIMK, HIDN, 2><<<dim3(DIMK/256, MAXMT - TOK/256), 512, 0, stream>>>(
        hbuf, nullptr, w2cat, out, mt_e, mt_r0, nmt, tok, TOK/256);
}

// Round 8
// 1306.706 us; speedup vs baseline: 1.1021x; 1.0279x over previous
//
#include <hip/hip_runtime.h>

typedef unsigned short u16;
typedef unsigned int u32;

#define TOK    8192      // T = BS*SLEN
#define DIMK   2048
#define HIDN   1792
#define NCAT   3584      // 2*HIDN (interleaved W1/W3 rows)
#define NEXP   8
#define NPAIR  16384     // T * TOPK
#define RROWS  18432     // routed rows capacity (16384 + 8*256 pad)
#define CROWS  26624     // combined rows capacity (TOK + RROWS)
#define MAXMT  104       // 32 shared tiles + 72 routed tiles

typedef float f32x4 __attribute__((ext_vector_type(4)));
typedef __bf16 bf16x8 __attribute__((ext_vector_type(8)));

__device__ __forceinline__ u16 f2bf(float f) {
    u32 u = __float_as_uint(f);
    u += 0x7fffu + ((u >> 16) & 1u);   // RNE
    return (u16)(u >> 16);
}
__device__ __forceinline__ void gll16(const void* g, void* l) {
    __builtin_amdgcn_global_load_lds((__attribute__((address_space(1))) void*)(g),
                                     (__attribute__((address_space(3))) void*)(l),
                                     16, 0, 0);
}

// ------ transpose + fp32->bf16 : In[z][R][C] -> Out[z][C][R]  ---------------
// ilv=0: row r -> r.  ilv=1/2: W1/W3 16-col-group interleave:
//   r -> (r&~15)*2 + (ilv==2 ? 16 : 0) + (r&15)
__global__ void transpose_f2bf(const float* __restrict__ In, u16* __restrict__ Out,
                               int R, int C, size_t in_z, size_t out_z, size_t out_off,
                               int ilv) {
    __shared__ float tile[64 * 65];
    const float* in = In + (size_t)blockIdx.z * in_z;
    u16* out = Out + (size_t)blockIdx.z * out_z + out_off;
    int c0 = blockIdx.x * 64, r0 = blockIdx.y * 64;
    int tid = threadIdx.x;
#pragma unroll
    for (int p = 0; p < 16; ++p) {
        int idx = tid + p * 256;
        int r = idx >> 6, c = idx & 63;
        tile[r * 65 + c] = in[(size_t)(r0 + r) * C + c0 + c];
    }
    __syncthreads();
#pragma unroll
    for (int p = 0; p < 8; ++p) {
        int idx = (tid + p * 256) * 2;
        int ro = idx >> 6;
        int co = idx & 63;
        float v0 = tile[co * 65 + ro];
        float v1 = tile[(co + 1) * 65 + ro];
        u32 u = (u32)f2bf(v0) | ((u32)f2bf(v1) << 16);
        int orow = c0 + ro;
        if (ilv) orow = ((orow & ~15) << 1) + (ilv == 2 ? 16 : 0) + (orow & 15);
        *(u32*)&out[(size_t)orow * R + r0 + co] = u;
    }
}

// ---------------- fp32 -> bf16 elementwise (x) ------------------------------
__global__ void cvt_f2bf(const float* __restrict__ in, u16* __restrict__ out, int n8) {
    int i = blockIdx.x * 256 + threadIdx.x;
    if (i >= n8) return;
    const float4* p = (const float4*)in;
    float4 a = p[2 * i], b = p[2 * i + 1];
    union { u16 us[8]; uint4 u4; } o;
    o.us[0] = f2bf(a.x); o.us[1] = f2bf(a.y); o.us[2] = f2bf(a.z); o.us[3] = f2bf(a.w);
    o.us[4] = f2bf(b.x); o.us[5] = f2bf(b.y); o.us[6] = f2bf(b.z); o.us[7] = f2bf(b.w);
    ((uint4*)out)[i] = o.u4;
}

// ---------------- router: fp32 logits, softmax, top-2, slot alloc -----------
__global__ void router_k(const float* __restrict__ x, const float* __restrict__ gw,
                         const float* __restrict__ ebias, int* __restrict__ sel,
                         float* __restrict__ scor, int* __restrict__ pos,
                         int* __restrict__ counts) {
    int wave = threadIdx.x >> 6, lane = threadIdx.x & 63;
    int t = blockIdx.x * 4 + wave;
    const float* xr = x + (size_t)t * DIMK;
    float acc[8];
#pragma unroll
    for (int e = 0; e < 8; ++e) acc[e] = 0.f;
    for (int i = lane; i < DIMK; i += 64) {
        float xv = xr[i];
        float4 g0 = *(const float4*)(gw + (size_t)i * 8);
        float4 g1 = *(const float4*)(gw + (size_t)i * 8 + 4);
        acc[0] += xv * g0.x; acc[1] += xv * g0.y; acc[2] += xv * g0.z; acc[3] += xv * g0.w;
        acc[4] += xv * g1.x; acc[5] += xv * g1.y; acc[6] += xv * g1.z; acc[7] += xv * g1.w;
    }
#pragma unroll
    for (int off = 32; off; off >>= 1)
#pragma unroll
        for (int e = 0; e < 8; ++e) acc[e] += __shfl_xor(acc[e], off, 64);
    if (lane == 0) {
        float mx = acc[0];
#pragma unroll
        for (int e = 1; e < 8; ++e) mx = fmaxf(mx, acc[e]);
        float pv[8], psum = 0.f;
#pragma unroll
        for (int e = 0; e < 8; ++e) { pv[e] = __expf(acc[e] - mx); psum += pv[e]; }
        float inv = 1.f / psum;
        float bb[8];
#pragma unroll
        for (int e = 0; e < 8; ++e) { pv[e] *= inv; bb[e] = pv[e] + ebias[e]; }
        int e0 = 0;
#pragma unroll
        for (int e = 1; e < 8; ++e) if (bb[e] > bb[e0]) e0 = e;
        int e1 = (e0 == 0) ? 1 : 0;
#pragma unroll
        for (int e = 0; e < 8; ++e) if (e != e0 && bb[e] > bb[e1]) e1 = e;
        int i0 = t * 2, i1 = t * 2 + 1;
        sel[i0] = e0; sel[i1] = e1;
        scor[i0] = pv[e0]; scor[i1] = pv[e1];
        pos[i0] = atomicAdd(&counts[e0], 1);
        pos[i1] = atomicAdd(&counts[e1], 1);
    }
}

// ---------------- scan: 256-aligned segments + combined tile map ------------
__global__ void scan_k(const int* __restrict__ counts, int* __restrict__ seg,
                       int* __restrict__ mt_e, int* __restrict__ mt_r0,
                       int* __restrict__ nmt, int* __restrict__ nrows) {
    if (threadIdx.x == 0 && blockIdx.x == 0) {
        int ntl = 0;
        for (int i = 0; i < TOK / 256; ++i) { mt_e[ntl] = 8; mt_r0[ntl] = i * 256; ++ntl; }
        int off = TOK;
        for (int e = 0; e < NEXP; ++e) {
            seg[e] = off;
            int c = counts[e];
            int tl = (c + 255) >> 8;
            for (int j = 0; j < tl; ++j) { mt_e[ntl] = e; mt_r0[ntl] = off + (j << 8); ++ntl; }
            off += tl << 8;
        }
        *nmt = ntl;
        *nrows = off;
    }
}

// ---------------- dispatch: gather+scale to bf16, plus pad-row zeroing ------
__global__ void dispatch_k(const float* __restrict__ x, const int* __restrict__ sel,
                           const float* __restrict__ scor, const int* __restrict__ pos,
                           const int* __restrict__ counts, const int* __restrict__ seg,
                           u32* __restrict__ rin, int* __restrict__ tok) {
    int b = blockIdx.x;
    if (b < NPAIR) {
        int t = b >> 1;
        int e = sel[b];
        float s = scor[b];
        int row = seg[e] + pos[b];           // combined row (>= TOK)
        const float2* xr = (const float2*)(x + (size_t)t * DIMK);
        u32* orow = rin + (size_t)(row - TOK) * (DIMK / 2);
        for (int i = threadIdx.x; i < DIMK / 2; i += 256) {
            float2 v = xr[i];
            orow[i] = (u32)f2bf(v.x * s) | ((u32)f2bf(v.y * s) << 16);
        }
        if (threadIdx.x == 0) tok[row] = t;
    } else {
        int pb = b - NPAIR;
        int e = pb >> 8, j = pb & 255;
        int c = counts[e];
        int al = (c + 255) & ~255;
        if (c + j < al) {
            int row = seg[e] + c + j;
            u32* orow = rin + (size_t)(row - TOK) * (DIMK / 2);
            for (int i = threadIdx.x; i < DIMK / 2; i += 256) orow[i] = 0u;
            if (threadIdx.x == 0) tok[row] = -1;
        }
    }
}

// ================= 256x256 8-phase GEMM (m201 template, plain HIP) ==========
// A [rows][ASTR] bf16; B cat [9][ND][KD] bf16 (B^T per expert).
// LDS rows are 128 B; bank-spread swizzle: byte ^= (row&7)<<4 applied to BOTH
// the pre-swizzled staging source col and the ds_read col (rule #21).
// EPI 0: paired silu-mul -> bf16 H[r][ND/2]   (gemm1, W1/W3 interleaved)
// EPI 1: store f32 -> out (shared rows); EPI 2: atomicAdd f32 -> out[tok[r]].
#define LDA(mh, b) { \
    _Pragma("unroll") for (int m_ = 0; m_ < 4; ++m_) \
    _Pragma("unroll") for (int ks_ = 0; ks_ < 2; ++ks_) \
        aF[mh][m_][ks_] = *(const bf16x8*)(&lds[b][0][0] + aRow + ((mh)*4 + m_) * 2048 + cok[ks_]); }
#define LDB(nh, b) { \
    _Pragma("unroll") for (int n_ = 0; n_ < 2; ++n_) \
    _Pragma("unroll") for (int ks_ = 0; ks_ < 2; ++ks_) \
        bF[n_][ks_] = *(const bf16x8*)(&lds[b][1][0] + bRow + ((nh)*2 + n_) * 2048 + cok[ks_]); }
#define MFMAQ(mh, nh) { \
    _Pragma("unroll") for (int m_ = 0; m_ < 4; ++m_) \
    _Pragma("unroll") for (int n_ = 0; n_ < 2; ++n_) \
    _Pragma("unroll") for (int ks_ = 0; ks_ < 2; ++ks_) \
        acc[(mh)*4 + m_][(nh)*2 + n_] = __builtin_amdgcn_mfma_f32_16x16x32_bf16( \
            aF[mh][m_][ks_], bF[n_][ks_], acc[(mh)*4 + m_][(nh)*2 + n_], 0, 0, 0); }
#define SA(kt, half, b) do { \
    const char* s_ = gA + (size_t)(half) * (128 * ABS) + (size_t)(kt) * 128; \
    char* d_ = &lds[b][0][0] + (half) * 16384 + t16; \
    gll16(s_, d_); gll16(s_ + 64 * ABS, d_ + 8192); } while (0)
#define SB(kt, half, b) do { \
    const char* s_ = gB + (size_t)(half) * (128 * BBS) + (size_t)(kt) * 128; \
    char* d_ = &lds[b][1][0] + (half) * 16384 + t16; \
    gll16(s_, d_); gll16(s_ + 64 * BBS, d_ + 8192); } while (0)
#define PH_SYNC() \
    __builtin_amdgcn_s_barrier(); \
    asm volatile("s_waitcnt lgkmcnt(0)" ::: "memory"); \
    __builtin_amdgcn_sched_barrier(0); \
    __builtin_amdgcn_s_setprio(1)
#define PH_END() \
    __builtin_amdgcn_s_setprio(0); \
    __builtin_amdgcn_s_barrier()

template <int KD, int ND, int ASTR, int EPI>
__launch_bounds__(512, 2)
__global__ void gemm256(const u16* __restrict__ A0, const u16* __restrict__ A1,
                        const u16* __restrict__ Bcat, void* __restrict__ Obase,
                        const int* __restrict__ mt_e, const int* __restrict__ mt_r0,
                        const int* __restrict__ nmt, const int* __restrict__ tok,
                        int tile_off) {
    int my = blockIdx.y + tile_off;
    if (my >= *nmt) return;
    const int e = mt_e[my];
    const int r0 = mt_r0[my];
    const int c0 = blockIdx.x * 256;

    const u16* Ab;
    if constexpr (EPI == 0)
        Ab = (r0 < TOK) ? (A0 + (size_t)r0 * ASTR) : (A1 + (size_t)(r0 - TOK) * ASTR);
    else
        Ab = A0 + (size_t)r0 * ASTR;
    const u16* Bb = Bcat + (size_t)e * ND * KD + (size_t)c0 * KD;

    __shared__ char lds[2][2][32768];   // [dbuf][A/B][256x64 bf16]

    const int t = threadIdx.x;
    const int lane = t & 63;
    const int wid = t >> 6;
    const int wr = wid >> 2, wc = wid & 3;
    const int fr = lane & 15, fq = lane >> 4;
    // read-side swizzle: byte col = ((fq + 4*ks)*16) ^ ((row&7)<<4); row&7 == fr&7
    const int sx = (fr & 7) << 4;
    const int cok[2] = { (fq * 16) ^ sx, (fq * 16 + 64) ^ sx };
    const int aRow = (wr * 128 + fr) * 128;
    const int bRow = (wc * 64 + fr) * 128;
    const int t16 = t * 16;
    constexpr size_t ABS = (size_t)ASTR * 2;
    constexpr size_t BBS = (size_t)KD * 2;
    // staging: linear LDS dest (row=t>>3, col=(t&7)*16); source col pre-inverse-swizzled
    const int scb = ((t & 7) * 16) ^ (((t >> 3) & 7) << 4);
    const char* gA = (const char*)Ab + (size_t)(t >> 3) * ABS + scb;
    const char* gB = (const char*)Bb + (size_t)(t >> 3) * BBS + scb;

    f32x4 acc[8][4];
    const f32x4 zz = {0.f, 0.f, 0.f, 0.f};
#pragma unroll
    for (int m = 0; m < 8; ++m)
#pragma unroll
        for (int n = 0; n < 4; ++n) acc[m][n] = zz;
    bf16x8 aF[2][4][2], bF[2][2];

    constexpr int NT = KD / 64;
    constexpr int NITER = NT / 2;

    // prologue: A(0),B(0)->buf0, A(1)->buf1; wait K-tile 0 landed
    SA(0, 0, 0); SA(0, 1, 0); SB(0, 0, 0); SB(0, 1, 0);
    SA(1, 0, 1); SA(1, 1, 1);
    asm volatile("s_waitcnt vmcnt(4)" ::: "memory");
    __builtin_amdgcn_s_barrier();

#pragma unroll 1
    for (int it = 0; it < NITER; ++it) {
        const int t0 = 2 * it;
        const bool pf = (t0 + 2 < NT);
        // ph1: Q(0,0) of t0 (buf0); stage B-lo(t0+1)->buf1
        LDA(0, 0); LDB(0, 0);
        SB(t0 + 1, 0, 1);
        PH_SYNC(); MFMAQ(0, 0); PH_END();
        // ph2: Q(1,0); stage B-hi(t0+1)->buf1   [buf0 A fully read after this]
        LDA(1, 0);
        SB(t0 + 1, 1, 1);
        PH_SYNC(); MFMAQ(1, 0); PH_END();
        // ph3: Q(0,1); stage A-lo(t0+2)->buf0   [buf0 B fully read after this]
        LDB(1, 0);
        if (pf) SA(t0 + 2, 0, 0);
        PH_SYNC(); MFMAQ(0, 1); PH_END();
        // ph4: Q(1,1); stage A-hi(t0+2)->buf0; vmcnt -> A(t0+1),B(t0+1) landed
        if (pf) { SA(t0 + 2, 1, 0); asm volatile("s_waitcnt vmcnt(4)" ::: "memory"); }
        else    { asm volatile("s_waitcnt vmcnt(0)" ::: "memory"); }
        PH_SYNC(); MFMAQ(1, 1); PH_END();
        // ph5: Q(0,0) of t0+1 (buf1); stage B-lo(t0+2)->buf0
        LDA(0, 1); LDB(0, 1);
        if (pf) SB(t0 + 2, 0, 0);
        PH_SYNC(); MFMAQ(0, 0); PH_END();
        // ph6: Q(1,0); stage B-hi(t0+2)->buf0   [buf1 A fully read after this]
        LDA(1, 1);
        if (pf) SB(t0 + 2, 1, 0);
        PH_SYNC(); MFMAQ(1, 0); PH_END();
        // ph7: Q(0,1); stage A-lo(t0+3)->buf1   [buf1 B fully read after this]
        LDB(1, 1);
        if (pf) SA(t0 + 3, 0, 1);
        PH_SYNC(); MFMAQ(0, 1); PH_END();
        // ph8: Q(1,1); stage A-hi(t0+3)->buf1; vmcnt -> A(t0+2),B(t0+2) landed
        if (pf) { SA(t0 + 3, 1, 1); asm volatile("s_waitcnt vmcnt(4)" ::: "memory"); }
        PH_SYNC(); MFMAQ(1, 1); PH_END();
    }

    // epilogue
    if constexpr (EPI == 0) {
        // W1/W3 interleaved in 16-col groups: n even = W1, n+1 = W3 (same cols)
        u16* H = (u16*)Obase;
        constexpr int HST = ND / 2;
#pragma unroll
        for (int m = 0; m < 8; ++m) {
#pragma unroll
            for (int n = 0; n < 4; n += 2) {
                int gc = (c0 + wc * 64 + n * 16) / 2 + fr;
#pragma unroll
                for (int i = 0; i < 4; ++i) {
                    int gr = r0 + wr * 128 + m * 16 + fq * 4 + i;
                    float p1 = acc[m][n][i], p3 = acc[m][n + 1][i];
                    float h = p1 * p3 / (1.f + __expf(-p1));
                    H[(size_t)gr * HST + gc] = f2bf(h);
                }
            }
        }
    } else if constexpr (EPI == 1) {
        float* O = (float*)Obase;
#pragma unroll
        for (int m = 0; m < 8; ++m)
#pragma unroll
            for (int n = 0; n < 4; ++n) {
                int gc = c0 + wc * 64 + n * 16 + fr;
#pragma unroll
                for (int i = 0; i < 4; ++i) {
                    int gr = r0 + wr * 128 + m * 16 + fq * 4 + i;
                    O[(size_t)gr * ND + gc] = acc[m][n][i];
                }
            }
    } else {
        float* O = (float*)Obase;
#pragma unroll
        for (int m = 0; m < 8; ++m) {
            int tk[4];
#pragma unroll
            for (int i = 0; i < 4; ++i)
                tk[i] = tok[r0 + wr * 128 + m * 16 + fq * 4 + i];
#pragma unroll
            for (int n = 0; n < 4; ++n) {
                int gc = c0 + wc * 64 + n * 16 + fr;
#pragma unroll
                for (int i = 0; i < 4; ++i)
                    if (tk[i] >= 0) atomicAdd(&O[(size_t)tk[i] * ND + gc], acc[m][n][i]);
            }
        }
    }
}

// ----------------------------------------------------------------------------
extern "C" void kernel_launch(void* const* d_in, const int* in_sizes, int n_in,
                              void* d_out, int out_size, void* d_ws, size_t ws_size,
                              hipStream_t stream) {
    const float* x    = (const float*)d_in[0];
    const float* gw   = (const float*)d_in[1];
    const float* w1   = (const float*)d_in[2];
    const float* w2   = (const float*)d_in[3];
    const float* w3   = (const float*)d_in[4];
    const float* sw1  = (const float*)d_in[5];
    const float* sw2  = (const float*)d_in[6];
    const float* sw3  = (const float*)d_in[7];
    const float* ebias= (const float*)d_in[8];
    float* out = (float*)d_out;

    char* p = (char*)d_ws;
    auto alloc = [&](size_t b) -> char* {
        char* r = p; p += (b + 255) & ~(size_t)255; return r;
    };
    u16* wcat  = (u16*)alloc((size_t)9 * NCAT * DIMK * 2);   // [e<=8][3584 ilv][2048]
    u16* w2cat = (u16*)alloc((size_t)9 * DIMK * HIDN * 2);   // [e<=8][2048][1792]
    u16* xb    = (u16*)alloc((size_t)TOK * DIMK * 2);
    u16* rin   = (u16*)alloc((size_t)RROWS * DIMK * 2);
    u16* hbuf  = (u16*)alloc((size_t)CROWS * HIDN * 2);      // silu-mul'd h
    int* sel    = (int*)alloc(NPAIR * 4);
    float* scor = (float*)alloc(NPAIR * 4);
    int* pos    = (int*)alloc(NPAIR * 4);
    int* counts = (int*)alloc(64);
    int* seg    = (int*)alloc(64);
    int* mt_e   = (int*)alloc(MAXMT * 4);
    int* mt_r0  = (int*)alloc(MAXMT * 4);
    int* nmt    = (int*)alloc(64);
    int* nrows  = (int*)alloc(64);
    int* tok    = (int*)alloc(CROWS * 4);

    hipMemsetAsync(counts, 0, NEXP * 4, stream);

    // weights -> bf16 transposed; wcat = interleaved [W1|W3], expert 8 = shared
    size_t wz = (size_t)NCAT * DIMK;        // 3584*2048
    size_t w2z = (size_t)DIMK * HIDN;       // 2048*1792
    transpose_f2bf<<<dim3(HIDN/64, DIMK/64, NEXP), 256, 0, stream>>>(
        w1, wcat, DIMK, HIDN, (size_t)DIMK*HIDN, wz, 0, 1);
    transpose_f2bf<<<dim3(HIDN/64, DIMK/64, NEXP), 256, 0, stream>>>(
        w3, wcat, DIMK, HIDN, (size_t)DIMK*HIDN, wz, 0, 2);
    transpose_f2bf<<<dim3(HIDN/64, DIMK/64, 1), 256, 0, stream>>>(
        sw1, wcat, DIMK, HIDN, 0, 0, 8*wz, 1);
    transpose_f2bf<<<dim3(HIDN/64, DIMK/64, 1), 256, 0, stream>>>(
        sw3, wcat, DIMK, HIDN, 0, 0, 8*wz, 2);
    transpose_f2bf<<<dim3(DIMK/64, HIDN/64, NEXP), 256, 0, stream>>>(
        w2, w2cat, HIDN, DIMK, (size_t)HIDN*DIMK, w2z, 0, 0);
    transpose_f2bf<<<dim3(DIMK/64, HIDN/64, 1), 256, 0, stream>>>(
        sw2, w2cat, HIDN, DIMK, 0, 0, 8*w2z, 0);

    cvt_f2bf<<<(TOK * DIMK / 8 + 255) / 256, 256, 0, stream>>>(x, xb, TOK * DIMK / 8);
    router_k<<<TOK / 4, 256, 0, stream>>>(x, gw, ebias, sel, scor, pos, counts);
    scan_k<<<1, 64, 0, stream>>>(counts, seg, mt_e, mt_r0, nmt, nrows);
    dispatch_k<<<NPAIR + NEXP * 256, 256, 0, stream>>>(x, sel, scor, pos, counts, seg,
                                                       (u32*)rin, tok);

    // gemm1: h = silu(A@W1)*(A@W3) fused via interleaved weights
    gemm256<DIMK, NCAT, DIMK, 0><<<dim3(NCAT/256, MAXMT), 512, 0, stream>>>(
        xb, rin, wcat, hbuf, mt_e, mt_r0, nmt, nullptr, 0);
    // gemm2 shared tiles: plain f32 store (initializes every out row)
    gemm256<HIDN, DIMK, HIDN, 1><<<dim3(DIMK/256, TOK/256), 512, 0, stream>>>(
        hbuf, nullptr, w2cat, out, mt_e, mt_r0, nmt, nullptr, 0);
    // gemm2 routed tiles: atomic scatter-add into out
    gemm256<HIDN, DIMK, HIDN, 2><<<dim3(DIMK/256, MAXMT - TOK/256), 512, 0, stream>>>(
        hbuf, nullptr, w2cat, out, mt_e, mt_r0, nmt, tok, TOK/256);
}

// Round 9
// 1284.677 us; speedup vs baseline: 1.1210x; 1.0171x over previous
//
#include <hip/hip_runtime.h>

typedef unsigned short u16;
typedef unsigned int u32;

#define TOK    8192      // T = BS*SLEN
#define DIMK   2048
#define HIDN   1792
#define NCAT   3584      // 2*HIDN (interleaved W1/W3 rows)
#define NEXP   8
#define NPAIR  16384     // T * TOPK
#define RROWS  18432     // routed rows capacity (16384 + 8*256 pad)
#define CROWS  26624     // combined rows capacity (TOK + RROWS)
#define MAXMT  104       // 32 shared tiles + 72 routed tiles

typedef float f32x4 __attribute__((ext_vector_type(4)));
typedef __bf16 bf16x8 __attribute__((ext_vector_type(8)));

__device__ __forceinline__ u16 f2bf(float f) {
    u32 u = __float_as_uint(f);
    u += 0x7fffu + ((u >> 16) & 1u);   // RNE
    return (u16)(u >> 16);
}
__device__ __forceinline__ void gll16(const void* g, void* l) {
    __builtin_amdgcn_global_load_lds((__attribute__((address_space(1))) void*)(g),
                                     (__attribute__((address_space(3))) void*)(l),
                                     16, 0, 0);
}

// ------ transpose + fp32->bf16 : In[z][R][C] -> Out[z][C][R]  ---------------
// ilv=0: row r -> r.  ilv=1/2: W1/W3 16-col-group interleave:
//   r -> (r&~15)*2 + (ilv==2 ? 16 : 0) + (r&15)
__global__ void transpose_f2bf(const float* __restrict__ In, u16* __restrict__ Out,
                               int R, int C, size_t in_z, size_t out_z, size_t out_off,
                               int ilv) {
    __shared__ float tile[64 * 65];
    const float* in = In + (size_t)blockIdx.z * in_z;
    u16* out = Out + (size_t)blockIdx.z * out_z + out_off;
    int c0 = blockIdx.x * 64, r0 = blockIdx.y * 64;
    int tid = threadIdx.x;
#pragma unroll
    for (int p = 0; p < 16; ++p) {
        int idx = tid + p * 256;
        int r = idx >> 6, c = idx & 63;
        tile[r * 65 + c] = in[(size_t)(r0 + r) * C + c0 + c];
    }
    __syncthreads();
#pragma unroll
    for (int p = 0; p < 8; ++p) {
        int idx = (tid + p * 256) * 2;
        int ro = idx >> 6;
        int co = idx & 63;
        float v0 = tile[co * 65 + ro];
        float v1 = tile[(co + 1) * 65 + ro];
        u32 u = (u32)f2bf(v0) | ((u32)f2bf(v1) << 16);
        int orow = c0 + ro;
        if (ilv) orow = ((orow & ~15) << 1) + (ilv == 2 ? 16 : 0) + (orow & 15);
        *(u32*)&out[(size_t)orow * R + r0 + co] = u;
    }
}

// ---------------- fp32 -> bf16 elementwise (x) ------------------------------
__global__ void cvt_f2bf(const float* __restrict__ in, u16* __restrict__ out, int n8) {
    int i = blockIdx.x * 256 + threadIdx.x;
    if (i >= n8) return;
    const float4* p = (const float4*)in;
    float4 a = p[2 * i], b = p[2 * i + 1];
    union { u16 us[8]; uint4 u4; } o;
    o.us[0] = f2bf(a.x); o.us[1] = f2bf(a.y); o.us[2] = f2bf(a.z); o.us[3] = f2bf(a.w);
    o.us[4] = f2bf(b.x); o.us[5] = f2bf(b.y); o.us[6] = f2bf(b.z); o.us[7] = f2bf(b.w);
    ((uint4*)out)[i] = o.u4;
}

// ---------------- router: fp32 logits, softmax, top-2, slot alloc -----------
__global__ void router_k(const float* __restrict__ x, const float* __restrict__ gw,
                         const float* __restrict__ ebias, int* __restrict__ sel,
                         float* __restrict__ scor, int* __restrict__ pos,
                         int* __restrict__ counts) {
    int wave = threadIdx.x >> 6, lane = threadIdx.x & 63;
    int t = blockIdx.x * 4 + wave;
    const float* xr = x + (size_t)t * DIMK;
    float acc[8];
#pragma unroll
    for (int e = 0; e < 8; ++e) acc[e] = 0.f;
    for (int i = lane; i < DIMK; i += 64) {
        float xv = xr[i];
        float4 g0 = *(const float4*)(gw + (size_t)i * 8);
        float4 g1 = *(const float4*)(gw + (size_t)i * 8 + 4);
        acc[0] += xv * g0.x; acc[1] += xv * g0.y; acc[2] += xv * g0.z; acc[3] += xv * g0.w;
        acc[4] += xv * g1.x; acc[5] += xv * g1.y; acc[6] += xv * g1.z; acc[7] += xv * g1.w;
    }
#pragma unroll
    for (int off = 32; off; off >>= 1)
#pragma unroll
        for (int e = 0; e < 8; ++e) acc[e] += __shfl_xor(acc[e], off, 64);
    if (lane == 0) {
        float mx = acc[0];
#pragma unroll
        for (int e = 1; e < 8; ++e) mx = fmaxf(mx, acc[e]);
        float pv[8], psum = 0.f;
#pragma unroll
        for (int e = 0; e < 8; ++e) { pv[e] = __expf(acc[e] - mx); psum += pv[e]; }
        float inv = 1.f / psum;
        float bb[8];
#pragma unroll
        for (int e = 0; e < 8; ++e) { pv[e] *= inv; bb[e] = pv[e] + ebias[e]; }
        int e0 = 0;
#pragma unroll
        for (int e = 1; e < 8; ++e) if (bb[e] > bb[e0]) e0 = e;
        int e1 = (e0 == 0) ? 1 : 0;
#pragma unroll
        for (int e = 0; e < 8; ++e) if (e != e0 && bb[e] > bb[e1]) e1 = e;
        int i0 = t * 2, i1 = t * 2 + 1;
        sel[i0] = e0; sel[i1] = e1;
        scor[i0] = pv[e0]; scor[i1] = pv[e1];
        pos[i0] = atomicAdd(&counts[e0], 1);
        pos[i1] = atomicAdd(&counts[e1], 1);
    }
}

// ---------------- scan: 256-aligned segments + combined tile map ------------
__global__ void scan_k(const int* __restrict__ counts, int* __restrict__ seg,
                       int* __restrict__ mt_e, int* __restrict__ mt_r0,
                       int* __restrict__ nmt, int* __restrict__ nrows) {
    if (threadIdx.x == 0 && blockIdx.x == 0) {
        int ntl = 0;
        for (int i = 0; i < TOK / 256; ++i) { mt_e[ntl] = 8; mt_r0[ntl] = i * 256; ++ntl; }
        int off = TOK;
        for (int e = 0; e < NEXP; ++e) {
            seg[e] = off;
            int c = counts[e];
            int tl = (c + 255) >> 8;
            for (int j = 0; j < tl; ++j) { mt_e[ntl] = e; mt_r0[ntl] = off + (j << 8); ++ntl; }
            off += tl << 8;
        }
        *nmt = ntl;
        *nrows = off;
    }
}

// ---------------- dispatch: gather+scale to bf16, plus pad-row zeroing ------
__global__ void dispatch_k(const float* __restrict__ x, const int* __restrict__ sel,
                           const float* __restrict__ scor, const int* __restrict__ pos,
                           const int* __restrict__ counts, const int* __restrict__ seg,
                           u32* __restrict__ rin, int* __restrict__ tok) {
    int b = blockIdx.x;
    if (b < NPAIR) {
        int t = b >> 1;
        int e = sel[b];
        float s = scor[b];
        int row = seg[e] + pos[b];           // combined row (>= TOK)
        const float2* xr = (const float2*)(x + (size_t)t * DIMK);
        u32* orow = rin + (size_t)(row - TOK) * (DIMK / 2);
        for (int i = threadIdx.x; i < DIMK / 2; i += 256) {
            float2 v = xr[i];
            orow[i] = (u32)f2bf(v.x * s) | ((u32)f2bf(v.y * s) << 16);
        }
        if (threadIdx.x == 0) tok[row] = t;
    } else {
        int pb = b - NPAIR;
        int e = pb >> 8, j = pb & 255;
        int c = counts[e];
        int al = (c + 255) & ~255;
        if (c + j < al) {
            int row = seg[e] + c + j;
            u32* orow = rin + (size_t)(row - TOK) * (DIMK / 2);
            for (int i = threadIdx.x; i < DIMK / 2; i += 256) orow[i] = 0u;
            if (threadIdx.x == 0) tok[row] = -1;
        }
    }
}

// ================= 256x256 8-phase GEMM (m201 template, plain HIP) ==========
// A [rows][ASTR] bf16; B cat [9][ND][KD] bf16 (B^T per expert).
// LDS rows are 128 B; bank-spread swizzle: byte ^= (row&7)<<4 on BOTH sides.
// 1-D grid + bijective XCD-chunked swizzle (nwg % 8 == 0 always): blocks that
// share an A-panel (consecutive w, x-fastest) land on the SAME XCD's L2.
// EPI 0: paired silu-mul -> bf16 H[r][ND/2]   (gemm1, W1/W3 interleaved)
// EPI 1: store f32 -> out (shared rows); EPI 2: atomicAdd f32 -> out[tok[r]].
#define LDA(mh, b) { \
    _Pragma("unroll") for (int m_ = 0; m_ < 4; ++m_) \
    _Pragma("unroll") for (int ks_ = 0; ks_ < 2; ++ks_) \
        aF[mh][m_][ks_] = *(const bf16x8*)(&lds[b][0][0] + aRow + ((mh)*4 + m_) * 2048 + cok[ks_]); }
#define LDB(nh, b) { \
    _Pragma("unroll") for (int n_ = 0; n_ < 2; ++n_) \
    _Pragma("unroll") for (int ks_ = 0; ks_ < 2; ++ks_) \
        bF[n_][ks_] = *(const bf16x8*)(&lds[b][1][0] + bRow + ((nh)*2 + n_) * 2048 + cok[ks_]); }
#define MFMAQ(mh, nh) { \
    _Pragma("unroll") for (int m_ = 0; m_ < 4; ++m_) \
    _Pragma("unroll") for (int n_ = 0; n_ < 2; ++n_) \
    _Pragma("unroll") for (int ks_ = 0; ks_ < 2; ++ks_) \
        acc[(mh)*4 + m_][(nh)*2 + n_] = __builtin_amdgcn_mfma_f32_16x16x32_bf16( \
            aF[mh][m_][ks_], bF[n_][ks_], acc[(mh)*4 + m_][(nh)*2 + n_], 0, 0, 0); }
#define SA(kt, half, b) do { \
    const char* s_ = gA + (size_t)(half) * (128 * ABS) + (size_t)(kt) * 128; \
    char* d_ = &lds[b][0][0] + (half) * 16384 + t16; \
    gll16(s_, d_); gll16(s_ + 64 * ABS, d_ + 8192); } while (0)
#define SB(kt, half, b) do { \
    const char* s_ = gB + (size_t)(half) * (128 * BBS) + (size_t)(kt) * 128; \
    char* d_ = &lds[b][1][0] + (half) * 16384 + t16; \
    gll16(s_, d_); gll16(s_ + 64 * BBS, d_ + 8192); } while (0)
#define PH_SYNC() \
    __builtin_amdgcn_s_barrier(); \
    asm volatile("s_waitcnt lgkmcnt(0)" ::: "memory"); \
    __builtin_amdgcn_sched_barrier(0); \
    __builtin_amdgcn_s_setprio(1)
#define PH_END() \
    __builtin_amdgcn_s_setprio(0); \
    __builtin_amdgcn_s_barrier()

template <int KD, int ND, int ASTR, int EPI>
__launch_bounds__(512, 2)
__global__ void gemm256(const u16* __restrict__ A0, const u16* __restrict__ A1,
                        const u16* __restrict__ Bcat, void* __restrict__ Obase,
                        const int* __restrict__ mt_e, const int* __restrict__ mt_r0,
                        const int* __restrict__ nmt, const int* __restrict__ tok,
                        int tile_off) {
    constexpr int NXB = ND / 256;
    // bijective XCD swizzle: nwg % 8 == 0 for all our launches
    const int q8 = (int)gridDim.x >> 3;
    const int b0 = (int)blockIdx.x;
    const int w = (b0 & 7) * q8 + (b0 >> 3);
    const int my = w / NXB + tile_off;
    if (my >= *nmt) return;
    const int e = mt_e[my];
    const int r0 = mt_r0[my];
    const int c0 = (w % NXB) * 256;

    const u16* Ab;
    if constexpr (EPI == 0)
        Ab = (r0 < TOK) ? (A0 + (size_t)r0 * ASTR) : (A1 + (size_t)(r0 - TOK) * ASTR);
    else
        Ab = A0 + (size_t)r0 * ASTR;
    const u16* Bb = Bcat + (size_t)e * ND * KD + (size_t)c0 * KD;

    __shared__ char lds[2][2][32768];   // [dbuf][A/B][256x64 bf16]

    const int t = threadIdx.x;
    const int lane = t & 63;
    const int wid = t >> 6;
    const int wr = wid >> 2, wc = wid & 3;
    const int fr = lane & 15, fq = lane >> 4;
    // read-side swizzle: byte col = ((fq + 4*ks)*16) ^ ((row&7)<<4); row&7 == fr&7
    const int sx = (fr & 7) << 4;
    const int cok[2] = { (fq * 16) ^ sx, (fq * 16 + 64) ^ sx };
    const int aRow = (wr * 128 + fr) * 128;
    const int bRow = (wc * 64 + fr) * 128;
    const int t16 = t * 16;
    constexpr size_t ABS = (size_t)ASTR * 2;
    constexpr size_t BBS = (size_t)KD * 2;
    // staging: linear LDS dest (row=t>>3, col=(t&7)*16); source col pre-inverse-swizzled
    const int scb = ((t & 7) * 16) ^ (((t >> 3) & 7) << 4);
    const char* gA = (const char*)Ab + (size_t)(t >> 3) * ABS + scb;
    const char* gB = (const char*)Bb + (size_t)(t >> 3) * BBS + scb;

    f32x4 acc[8][4];
    const f32x4 zz = {0.f, 0.f, 0.f, 0.f};
#pragma unroll
    for (int m = 0; m < 8; ++m)
#pragma unroll
        for (int n = 0; n < 4; ++n) acc[m][n] = zz;
    bf16x8 aF[2][4][2], bF[2][2];

    constexpr int NT = KD / 64;
    constexpr int NITER = NT / 2;

    // prologue: A(0),B(0)->buf0, A(1)->buf1; wait K-tile 0 landed
    SA(0, 0, 0); SA(0, 1, 0); SB(0, 0, 0); SB(0, 1, 0);
    SA(1, 0, 1); SA(1, 1, 1);
    asm volatile("s_waitcnt vmcnt(4)" ::: "memory");
    __builtin_amdgcn_s_barrier();

#pragma unroll 1
    for (int it = 0; it < NITER; ++it) {
        const int t0 = 2 * it;
        const bool pf = (t0 + 2 < NT);
        // ph1: Q(0,0) of t0 (buf0); stage B-lo(t0+1)->buf1
        LDA(0, 0); LDB(0, 0);
        SB(t0 + 1, 0, 1);
        PH_SYNC(); MFMAQ(0, 0); PH_END();
        // ph2: Q(1,0); stage B-hi(t0+1)->buf1   [buf0 A fully read after this]
        LDA(1, 0);
        SB(t0 + 1, 1, 1);
        PH_SYNC(); MFMAQ(1, 0); PH_END();
        // ph3: Q(0,1); stage A-lo(t0+2)->buf0   [buf0 B fully read after this]
        LDB(1, 0);
        if (pf) SA(t0 + 2, 0, 0);
        PH_SYNC(); MFMAQ(0, 1); PH_END();
        // ph4: Q(1,1); stage A-hi(t0+2)->buf0; vmcnt -> A(t0+1),B(t0+1) landed
        if (pf) { SA(t0 + 2, 1, 0); asm volatile("s_waitcnt vmcnt(4)" ::: "memory"); }
        else    { asm volatile("s_waitcnt vmcnt(0)" ::: "memory"); }
        PH_SYNC(); MFMAQ(1, 1); PH_END();
        // ph5: Q(0,0) of t0+1 (buf1); stage B-lo(t0+2)->buf0
        LDA(0, 1); LDB(0, 1);
        if (pf) SB(t0 + 2, 0, 0);
        PH_SYNC(); MFMAQ(0, 0); PH_END();
        // ph6: Q(1,0); stage B-hi(t0+2)->buf0   [buf1 A fully read after this]
        LDA(1, 1);
        if (pf) SB(t0 + 2, 1, 0);
        PH_SYNC(); MFMAQ(1, 0); PH_END();
        // ph7: Q(0,1); stage A-lo(t0+3)->buf1   [buf1 B fully read after this]
        LDB(1, 1);
        if (pf) SA(t0 + 3, 0, 1);
        PH_SYNC(); MFMAQ(0, 1); PH_END();
        // ph8: Q(1,1); stage A-hi(t0+3)->buf1; vmcnt -> A(t0+2),B(t0+2) landed
        if (pf) { SA(t0 + 3, 1, 1); asm volatile("s_waitcnt vmcnt(4)" ::: "memory"); }
        PH_SYNC(); MFMAQ(1, 1); PH_END();
    }

    // epilogue
    if constexpr (EPI == 0) {
        // W1/W3 interleaved in 16-col groups: n even = W1, n+1 = W3 (same cols)
        u16* H = (u16*)Obase;
        constexpr int HST = ND / 2;
#pragma unroll
        for (int m = 0; m < 8; ++m) {
#pragma unroll
            for (int n = 0; n < 4; n += 2) {
                int gc = (c0 + wc * 64 + n * 16) / 2 + fr;
#pragma unroll
                for (int i = 0; i < 4; ++i) {
                    int gr = r0 + wr * 128 + m * 16 + fq * 4 + i;
                    float p1 = acc[m][n][i], p3 = acc[m][n + 1][i];
                    float h = p1 * p3 / (1.f + __expf(-p1));
                    H[(size_t)gr * HST + gc] = f2bf(h);
                }
            }
        }
    } else if constexpr (EPI == 1) {
        float* O = (float*)Obase;
#pragma unroll
        for (int m = 0; m < 8; ++m)
#pragma unroll
            for (int n = 0; n < 4; ++n) {
                int gc = c0 + wc * 64 + n * 16 + fr;
#pragma unroll
                for (int i = 0; i < 4; ++i) {
                    int gr = r0 + wr * 128 + m * 16 + fq * 4 + i;
                    O[(size_t)gr * ND + gc] = acc[m][n][i];
                }
            }
    } else {
        float* O = (float*)Obase;
#pragma unroll
        for (int m = 0; m < 8; ++m) {
            int tk[4];
#pragma unroll
            for (int i = 0; i < 4; ++i)
                tk[i] = tok[r0 + wr * 128 + m * 16 + fq * 4 + i];
#pragma unroll
            for (int n = 0; n < 4; ++n) {
                int gc = c0 + wc * 64 + n * 16 + fr;
#pragma unroll
                for (int i = 0; i < 4; ++i)
                    if (tk[i] >= 0) atomicAdd(&O[(size_t)tk[i] * ND + gc], acc[m][n][i]);
            }
        }
    }
}

// ----------------------------------------------------------------------------
extern "C" void kernel_launch(void* const* d_in, const int* in_sizes, int n_in,
                              void* d_out, int out_size, void* d_ws, size_t ws_size,
                              hipStream_t stream) {
    const float* x    = (const float*)d_in[0];
    const float* gw   = (const float*)d_in[1];
    const float* w1   = (const float*)d_in[2];
    const float* w2   = (const float*)d_in[3];
    const float* w3   = (const float*)d_in[4];
    const float* sw1  = (const float*)d_in[5];
    const float* sw2  = (const float*)d_in[6];
    const float* sw3  = (const float*)d_in[7];
    const float* ebias= (const float*)d_in[8];
    float* out = (float*)d_out;

    char* p = (char*)d_ws;
    auto alloc = [&](size_t b) -> char* {
        char* r = p; p += (b + 255) & ~(size_t)255; return r;
    };
    u16* wcat  = (u16*)alloc((size_t)9 * NCAT * DIMK * 2);   // [e<=8][3584 ilv][2048]
    u16* w2cat = (u16*)alloc((size_t)9 * DIMK * HIDN * 2);   // [e<=8][2048][1792]
    u16* xb    = (u16*)alloc((size_t)TOK * DIMK * 2);
    u16* rin   = (u16*)alloc((size_t)RROWS * DIMK * 2);
    u16* hbuf  = (u16*)alloc((size_t)CROWS * HIDN * 2);      // silu-mul'd h
    int* sel    = (int*)alloc(NPAIR * 4);
    float* scor = (float*)alloc(NPAIR * 4);
    int* pos    = (int*)alloc(NPAIR * 4);
    int* counts = (int*)alloc(64);
    int* seg    = (int*)alloc(64);
    int* mt_e   = (int*)alloc(MAXMT * 4);
    int* mt_r0  = (int*)alloc(MAXMT * 4);
    int* nmt    = (int*)alloc(64);
    int* nrows  = (int*)alloc(64);
    int* tok    = (int*)alloc(CROWS * 4);

    hipMemsetAsync(counts, 0, NEXP * 4, stream);

    // weights -> bf16 transposed; wcat = interleaved [W1|W3], expert 8 = shared
    size_t wz = (size_t)NCAT * DIMK;        // 3584*2048
    size_t w2z = (size_t)DIMK * HIDN;       // 2048*1792
    transpose_f2bf<<<dim3(HIDN/64, DIMK/64, NEXP), 256, 0, stream>>>(
        w1, wcat, DIMK, HIDN, (size_t)DIMK*HIDN, wz, 0, 1);
    transpose_f2bf<<<dim3(HIDN/64, DIMK/64, NEXP), 256, 0, stream>>>(
        w3, wcat, DIMK, HIDN, (size_t)DIMK*HIDN, wz, 0, 2);
    transpose_f2bf<<<dim3(HIDN/64, DIMK/64, 1), 256, 0, stream>>>(
        sw1, wcat, DIMK, HIDN, 0, 0, 8*wz, 1);
    transpose_f2bf<<<dim3(HIDN/64, DIMK/64, 1), 256, 0, stream>>>(
        sw3, wcat, DIMK, HIDN, 0, 0, 8*wz, 2);
    transpose_f2bf<<<dim3(DIMK/64, HIDN/64, NEXP), 256, 0, stream>>>(
        w2, w2cat, HIDN, DIMK, (size_t)HIDN*DIMK, w2z, 0, 0);
    transpose_f2bf<<<dim3(DIMK/64, HIDN/64, 1), 256, 0, stream>>>(
        sw2, w2cat, HIDN, DIMK, 0, 0, 8*w2z, 0);

    cvt_f2bf<<<(TOK * DIMK / 8 + 255) / 256, 256, 0, stream>>>(x, xb, TOK * DIMK / 8);
    router_k<<<TOK / 4, 256, 0, stream>>>(x, gw, ebias, sel, scor, pos, counts);
    scan_k<<<1, 64, 0, stream>>>(counts, seg, mt_e, mt_r0, nmt, nrows);
    dispatch_k<<<NPAIR + NEXP * 256, 256, 0, stream>>>(x, sel, scor, pos, counts, seg,
                                                       (u32*)rin, tok);

    // gemm1: h = silu(A@W1)*(A@W3) fused via interleaved weights
    // grid 14*104 = 1456 (%8==0), 1-D, XCD-swizzled inside
    gemm256<DIMK, NCAT, DIMK, 0><<<dim3(14 * MAXMT), 512, 0, stream>>>(
        xb, rin, wcat, hbuf, mt_e, mt_r0, nmt, nullptr, 0);
    // gemm2 shared tiles: plain f32 store; grid 8*32 = 256 (%8==0)
    gemm256<HIDN, DIMK, HIDN, 1><<<dim3(8 * (TOK / 256)), 512, 0, stream>>>(
        hbuf, nullptr, w2cat, out, mt_e, mt_r0, nmt, nullptr, 0);
    // gemm2 routed tiles: atomic scatter-add; grid 8*72 = 576 (%8==0)
    gemm256<HIDN, DIMK, HIDN, 2><<<dim3(8 * (MAXMT - TOK / 256)), 512, 0, stream>>>(
        hbuf, nullptr, w2cat, out, mt_e, mt_r0, nmt, tok, TOK / 256);
}